// Round 12
// baseline (194.106 us; speedup 1.0000x reference)
//
#include <hip/hip_runtime.h>

#define S_LEN 4096
#define NT 512
#define PER 8
#define RANK 8
#define BP 4160      // padded FFT buffer float count (max transpose addr 4151)
#define NHALF 2049   // half-spectrum gain table (k = 0..2048)

__device__ __forceinline__ void cmul(float& xr, float& xi, float cr, float ci){
    float tr = xr*cr - xi*ci;
    xi = xr*ci + xi*cr;
    xr = tr;
}

// 4-point DFT, in place. SIGN=-1 forward, SIGN=+1 inverse.
template<int SIGN>
__device__ __forceinline__ void dft4(float& ar,float& ai,float& br,float& bi,
                                     float& cr,float& ci,float& dr,float& di){
    float Ar=ar+cr, Ai=ai+ci;
    float Br=ar-cr, Bi=ai-ci;
    float Cr=br+dr, Ci=bi+di;
    float Dr, Di;
    if (SIGN < 0){ Dr = bi-di; Di = dr-br; }
    else         { Dr = di-bi; Di = br-dr; }
    ar=Ar+Cr; ai=Ai+Ci;
    br=Br+Dr; bi=Bi+Di;
    cr=Ar-Cr; ci=Ai-Ci;
    dr=Br-Dr; di=Bi-Di;
}

// 8-point DFT in registers, natural-order in and out.
// W8^{1,3} twiddles in h-factored form: 2 add + 2 mul each (vs 4m+2a cmul);
// compiler can't reassociate FP without fast-math, so do it by hand.
template<int SIGN>
__device__ __forceinline__ void dft8(float ur[8], float ui[8]){
    const float h = 0.70710678118654752f;
    float er0=ur[0], ei0=ui[0], er1=ur[2], ei1=ui[2];
    float er2=ur[4], ei2=ui[4], er3=ur[6], ei3=ui[6];
    float fr0=ur[1], fi0=ui[1], fr1=ur[3], fi1=ui[3];
    float fr2=ur[5], fi2=ui[5], fr3=ur[7], fi3=ui[7];
    dft4<SIGN>(er0,ei0, er1,ei1, er2,ei2, er3,ei3);
    dft4<SIGN>(fr0,fi0, fr1,fi1, fr2,fi2, fr3,fi3);
    {   float a = fr1, b = fi1;
        if (SIGN < 0){ fr1 = h*(a + b); fi1 = h*(b - a); }
        else         { fr1 = h*(a - b); fi1 = h*(a + b); }
    }
    {   float tr = fr2, ti = fi2;
        if (SIGN < 0){ fr2 =  ti; fi2 = -tr; }
        else         { fr2 = -ti; fi2 =  tr; }
    }
    {   float a = fr3, b = fi3;
        if (SIGN < 0){ fr3 = h*(b - a); fi3 = -h*(a + b); }
        else         { fr3 = -h*(a + b); fi3 = h*(a - b); }
    }
    ur[0]=er0+fr0; ui[0]=ei0+fi0;
    ur[1]=er1+fr1; ui[1]=ei1+fi1;
    ur[2]=er2+fr2; ui[2]=ei2+fi2;
    ur[3]=er3+fr3; ui[3]=ei3+fi3;
    ur[4]=er0-fr0; ui[4]=ei0-fi0;
    ur[5]=er1-fr1; ui[5]=ei1-fi1;
    ur[6]=er2-fr2; ui[6]=ei2-fi2;
    ur[7]=er3-fr3; ui[7]=ei3-fi3;
}

// balanced-tree twiddle powers + apply. frac = theta/(2pi) in [0,1):
// v_sin_f32/v_cos_f32 natively compute sin/cos(2pi*x) -> skip __sincosf's
// 1/(2pi) prescale + range reduction.
template<int SIGN>
__device__ __forceinline__ void twiddle8(float ur[8], float ui[8], float frac){
    float s = __builtin_amdgcn_sinf(frac);
    float c = __builtin_amdgcn_cosf(frac);
    const float w1i = (SIGN < 0) ? -s : s;
    const float w1r = c;
    float w2r = w1r*w1r - w1i*w1i, w2i = 2.0f*w1r*w1i;
    float w3r = w2r*w1r - w2i*w1i, w3i = w2r*w1i + w2i*w1r;
    float w4r = w2r*w2r - w2i*w2i, w4i = 2.0f*w2r*w2i;
    float w5r = w4r*w1r - w4i*w1i, w5i = w4r*w1i + w4i*w1r;
    float w6r = w3r*w3r - w3i*w3i, w6i = 2.0f*w3r*w3i;
    float w7r = w4r*w3r - w4i*w3i, w7i = w4r*w3i + w4i*w3r;
    cmul(ur[1], ui[1], w1r, w1i);
    cmul(ur[2], ui[2], w2r, w2i);
    cmul(ur[3], ui[3], w3r, w3i);
    cmul(ur[4], ui[4], w4r, w4i);
    cmul(ur[5], ui[5], w5r, w5i);
    cmul(ur[6], ui[6], w6r, w6i);
    cmul(ur[7], ui[7], w7r, w7i);
}

// gain for spectral index k (0..2048) for BOTH rows at once (shared bg + gathers).
__device__ __forceinline__ void gain_pair(int k, const float* hhA, const float* hhB,
    float alpha, const float* __restrict__ P2w, const float* __restrict__ P2b,
    float& ga, float& gb){
    float nf = (float)k * (1.0f/2048.0f);
    float tt = nf * 5.0f;
    float lb = __expf(-0.5f * tt * tt);
    float hd = 0.5f / (1.0f + __expf(-(nf - 0.6f) * 10.0f));
    float bg = fmaxf(1.0f + lb - hd, 0.0f);
    float scaled = nf * 4095.0f;
    float fl = floorf(scaled);
    int lo = (int)fl;
    int hi = (int)ceilf(scaled);
    float fr = scaled - fl;
    const float4* p2lo = (const float4*)(P2w + (size_t)lo * RANK);
    const float4* p2hi = (const float4*)(P2w + (size_t)hi * RANK);
    float4 a0 = p2lo[0], a1 = p2lo[1];
    float4 b0 = p2hi[0], b1 = p2hi[1];
    float blo = P2b[lo], bhi = P2b[hi];
    float dAlo = blo + hhA[0]*a0.x + hhA[1]*a0.y + hhA[2]*a0.z + hhA[3]*a0.w
                     + hhA[4]*a1.x + hhA[5]*a1.y + hhA[6]*a1.z + hhA[7]*a1.w;
    float dAhi = bhi + hhA[0]*b0.x + hhA[1]*b0.y + hhA[2]*b0.z + hhA[3]*b0.w
                     + hhA[4]*b1.x + hhA[5]*b1.y + hhA[6]*b1.z + hhA[7]*b1.w;
    float dBlo = blo + hhB[0]*a0.x + hhB[1]*a0.y + hhB[2]*a0.z + hhB[3]*a0.w
                     + hhB[4]*a1.x + hhB[5]*a1.y + hhB[6]*a1.z + hhB[7]*a1.w;
    float dBhi = bhi + hhB[0]*b0.x + hhB[1]*b0.y + hhB[2]*b0.z + hhB[3]*b0.w
                     + hhB[4]*b1.x + hhB[5]*b1.y + hhB[6]*b1.z + hhB[7]*b1.w;
    float dA = dAlo + (dAhi - dAlo) * fr;
    float dB = dBlo + (dBhi - dBlo) * fr;
    ga = fmaxf(bg + alpha * dA, 0.0f);
    gb = fmaxf(bg + alpha * dB, 0.0f);
}

// ============================================================================
// REAL-PACKING (2 rows/block, grid 1024) + PAIR-BASED middle phases (r11).
// r12 op-count cuts (no structure change):
//  - 5-step butterfly reductions (off=16..1, 32-lane groups) -> 16 LDS
//    partials per value; saves 80 shfl+add/thread. red[] 256 -> 512.
//  - twiddles via v_sin/v_cos revolutions form (frac in [0,1)).
//  - dft8 h-factored W8^{1,3} twiddles.
//  - 0.5 constants folded into gA/gB and gam4 at their single write sites
//    (self-pairs k=0/2048 stay consistent under the pair formula:
//     za = g'*(ar+ar) = g*ar).
// Unroll discipline (r10): "#pragma unroll 1" on ALL big outer loops —
// interleaved ~45-reg bodies are what spilled r5-r9. Inner r-loops fully
// unrolled (register arrays). VGPR wall (r2-r7): 64 -> 4 waves/SIMD; <64 cap
// spills. Occupancy hard-walled at 2 blocks/CU; lever is instruction count.
// ============================================================================

__global__ __launch_bounds__(NT, 4) void recip_mixer(
    const float* __restrict__ x,
    const float* __restrict__ Ur, const float* __restrict__ Ui,
    const float* __restrict__ Vr, const float* __restrict__ Vi,
    const float* __restrict__ Wr, const float* __restrict__ Wi,
    const float* __restrict__ P1w, const float* __restrict__ P1b,
    const float* __restrict__ P2w, const float* __restrict__ P2b,
    const float* __restrict__ alphap,
    float* __restrict__ out)
{
    __shared__ float sre[BP], sim[BP];
    __shared__ float gA[NHALF], gB[NHALF];   // PRESCALED by 0.5
    __shared__ float red[512];
    __shared__ float hidA[RANK], hidB[RANK];
    __shared__ float4 gam4[RANK];   // {gamAr, gamAi, gamBr, gamBi} per r, PRESCALED by 0.5
    __shared__ float pqs[64];

    const int t    = threadIdx.x;
    const int pairidx = blockIdx.x;
    const int lane = t & 63;
    const int wid  = t >> 6;

    float ur[8], ui[8];

    const int baseA = (t & 63) + 512 * (t >> 6);
    const int baseB = (t & 7) + 8*(t >> 6) + 520*((t >> 3) & 7);
    const int baseC = (t >> 3) + 520*(t & 7);

    const float* xa = x + (size_t)(2 * pairidx) * S_LEN;
    const float* xb = xa + S_LEN;

    // ================= forward FFT of w = x_a + i x_b =================
    {
#pragma unroll
        for (int c=0;c<8;c++){ ur[c] = xa[t + 512*c]; ui[c] = xb[t + 512*c]; }
        dft8<-1>(ur, ui);
#pragma unroll
        for (int e=0;e<8;e++){ sre[baseA + 64*e] = ur[e]; sim[baseA + 64*e] = ui[e]; }
    }
    __syncthreads();
    {
#pragma unroll
        for (int m=0;m<8;m++){ ur[m] = sre[t + 512*m]; ui[m] = sim[t + 512*m]; }
        twiddle8<-1>(ur, ui, (float)(t >> 6) * (1.0f/64.0f));
        dft8<-1>(ur, ui);
        __syncthreads();
#pragma unroll
        for (int e=0;e<8;e++){ sre[baseB + 64*e] = ur[e]; sim[baseB + 64*e] = ui[e]; }
    }
    __syncthreads();
    {
#pragma unroll
        for (int m=0;m<8;m++){ ur[m] = sre[t + 520*m]; ui[m] = sim[t + 520*m]; }
        twiddle8<-1>(ur, ui, (float)(t >> 3) * (1.0f/512.0f));
        dft8<-1>(ur, ui);
        __syncthreads();
#pragma unroll
        for (int e=0;e<8;e++){ sre[baseC + 64*e] = ur[e]; sim[baseC + 64*e] = ui[e]; }
    }
    __syncthreads();
    {
#pragma unroll
        for (int m=0;m<8;m++){ ur[m] = sre[t + 520*m]; ui[m] = sim[t + 520*m]; }
        twiddle8<-1>(ur, ui, (float)t * (1.0f/4096.0f));
        dft8<-1>(ur, ui);
        __syncthreads();
#pragma unroll
        for (int e=0;e<8;e++){ sre[t + 512*e] = ur[e]; sim[t + 512*e] = ui[e]; }
    }
    __syncthreads();   // middle phases read other threads' (k, N-k) slots

    // ===== phase 1: hidden for BOTH rows — pair-based (4 pairs/thread)
    {
        float ha[RANK], hb[RANK];
#pragma unroll
        for (int r = 0; r < RANK; r++){ ha[r] = 0.0f; hb[r] = 0.0f; }
#pragma unroll 1
        for (int i = 0; i < 4; i++) {
            int k = t + 512 * i;
            int j = (S_LEN - k) & (S_LEN - 1);
            float jm = (k == 0) ? 0.0f : 1.0f;   // kill j-side weights for self-pair
            float ar = sre[k], ai = sim[k];
            float br = sre[j], bi = sim[j];
            float zar = 0.5f*(ar + br), zai = 0.5f*(ai - bi);
            float zbr = 0.5f*(ai + bi), zbi = 0.5f*(br - ar);
#pragma unroll
            for (int r = 0; r < RANK; r++) {
                const float* P1r = P1w + r * (2 * S_LEN);
                float p0k = P1r[k],        p1k = P1r[S_LEN + k];
                float p0j = P1r[j],        p1j = P1r[S_LEN + j];
                float us = fmaf(jm, p0j, p0k);    // p0k + p0j
                float ud = fmaf(-jm, p1j, p1k);   // p1k - p1j
                ha[r] += zar * us + zai * ud;
                hb[r] += zbr * us + zbi * ud;
            }
        }
        if (t == 0) {
            // self-pair k = 2048: za = Re W (zai=0), zb = Im W (zbi=0)
            float ar = sre[2048], ai = sim[2048];
#pragma unroll
            for (int r = 0; r < RANK; r++) {
                float p0 = P1w[r * (2 * S_LEN) + 2048];
                ha[r] += ar * p0;
                hb[r] += ai * p0;
            }
        }
#pragma unroll
        for (int r = 0; r < RANK; r++) {
#pragma unroll
            for (int off = 16; off > 0; off >>= 1){
                ha[r] += __shfl_xor(ha[r], off, 64);
                hb[r] += __shfl_xor(hb[r], off, 64);
            }
        }
        if ((lane & 31) == 0) {
            int g = wid * 2 + (lane >> 5);   // 0..15
#pragma unroll
            for (int r = 0; r < RANK; r++){
                red[g * 16 + r]     = ha[r];
                red[g * 16 + 8 + r] = hb[r];
            }
        }
        __syncthreads();
        if (t < 16) {
            float v = 0.0f;
#pragma unroll
            for (int g = 0; g < 16; g++) v += red[g * 16 + t];
            float res = fmaxf(v + P1b[t & 7], 0.0f);
            if (t < 8) hidA[t] = res; else hidB[t - 8] = res;
        }
        __syncthreads();
    }

    // ===== phase 2a: half-spectrum gain tables gA/gB[0..2048], PRESCALED 0.5
    // (each thread writes only its own k set {t+512i} (+2048 by t0); all later
    //  reads are by the SAME thread -> no barrier needed after this phase)
    {
        float hhA[RANK], hhB[RANK];
#pragma unroll
        for (int r = 0; r < RANK; r++){ hhA[r] = hidA[r]; hhB[r] = hidB[r]; }
        const float alpha = alphap[0];
#pragma unroll 1
        for (int i = 0; i < 4; i++) {
            int k = t + 512 * i;           // 0..2047
            float ga, gb;
            gain_pair(k, hhA, hhB, alpha, P2w, P2b, ga, gb);
            gA[k] = 0.5f * ga; gB[k] = 0.5f * gb;
        }
        if (t == 0) {
            float ga, gb;
            gain_pair(2048, hhA, hhB, alpha, P2w, P2b, ga, gb);
            gA[2048] = 0.5f * ga; gB[2048] = 0.5f * gb;
        }
    }
    // no __syncthreads: own-slot gain reads only from here on

    // ===== phase 2b p-pass: pair-based (4 pairs/thread), rows A+B
    {
        float pAr[RANK], pAi[RANK], pBr[RANK], pBi[RANK];
#pragma unroll
        for (int r = 0; r < RANK; r++){ pAr[r]=0.f; pAi[r]=0.f; pBr[r]=0.f; pBi[r]=0.f; }
#pragma unroll 1
        for (int i = 0; i < 4; i++) {
            int k = t + 512 * i;
            int j = (S_LEN - k) & (S_LEN - 1);
            float jm = (k == 0) ? 0.0f : 1.0f;
            float ar = sre[k], ai = sim[k];
            float br = sre[j], bi = sim[j];
            float ga = gA[k], gb = gB[k];       // prescaled 0.5*g
            float zar = ga*(ar + br), zai = ga*(ai - bi);
            float zbr = gb*(ai + bi), zbi = gb*(br - ar);
#pragma unroll
            for (int r = 0; r < RANK; r++) {
                const float* Urr = Ur + r * S_LEN;
                const float* Uir = Ui + r * S_LEN;
                float ukr = Urr[k], uki = Uir[k];
                float ujr = Urr[j], uji = Uir[j];
                float us = fmaf(jm, ujr, ukr);    // ukr + ujr
                float ud = fmaf(-jm, ujr, ukr);   // ukr - ujr
                float vs = fmaf(jm, uji, uki);    // uki + uji
                float vd = fmaf(-jm, uji, uki);   // uki - uji
                pAr[r] += zar * us - zai * vd;
                pAi[r] += zar * vs + zai * ud;
                pBr[r] += zbr * us - zbi * vd;
                pBi[r] += zbr * vs + zbi * ud;
            }
        }
        if (t == 0) {
            float ar = sre[2048], ai = sim[2048];
            float zar = gA[2048] * (ar + ar);   // = g*ar (gain prescaled)
            float zbr = gB[2048] * (ai + ai);   // = g*ai
#pragma unroll
            for (int r = 0; r < RANK; r++) {
                float ukr = Ur[r * S_LEN + 2048], uki = Ui[r * S_LEN + 2048];
                pAr[r] += zar * ukr;  pAi[r] += zar * uki;
                pBr[r] += zbr * ukr;  pBi[r] += zbr * uki;
            }
        }
#pragma unroll
        for (int r = 0; r < RANK; r++) {
#pragma unroll
            for (int off = 16; off > 0; off >>= 1) {
                pAr[r] += __shfl_xor(pAr[r], off, 64);
                pAi[r] += __shfl_xor(pAi[r], off, 64);
                pBr[r] += __shfl_xor(pBr[r], off, 64);
                pBi[r] += __shfl_xor(pBi[r], off, 64);
            }
        }
        if ((lane & 31) == 0) {
            int g = wid * 2 + (lane >> 5);   // 0..15
#pragma unroll
            for (int r = 0; r < RANK; r++) {
                red[g * 32 + r]      = pAr[r];
                red[g * 32 + 8 + r]  = pAi[r];
                red[g * 32 + 16 + r] = pBr[r];
                red[g * 32 + 24 + r] = pBi[r];
            }
        }
        __syncthreads();
        if (t < 32) {
            float v = 0.0f;
#pragma unroll
            for (int g = 0; g < 16; g++) v += red[g * 32 + t];
            pqs[t] = v;
        }
        __syncthreads();
    }

    // ===== phase 2b q-pass: pair-based, rows A+B, then gamma
    {
        float qAr[RANK], qAi[RANK], qBr[RANK], qBi[RANK];
#pragma unroll
        for (int r = 0; r < RANK; r++){ qAr[r]=0.f; qAi[r]=0.f; qBr[r]=0.f; qBi[r]=0.f; }
#pragma unroll 1
        for (int i = 0; i < 4; i++) {
            int k = t + 512 * i;
            int j = (S_LEN - k) & (S_LEN - 1);
            float jm = (k == 0) ? 0.0f : 1.0f;
            float ar = sre[k], ai = sim[k];
            float br = sre[j], bi = sim[j];
            float ga = gA[k], gb = gB[k];       // prescaled 0.5*g
            float zar = ga*(ar + br), zai = ga*(ai - bi);
            float zbr = gb*(ai + bi), zbi = gb*(br - ar);
#pragma unroll
            for (int r = 0; r < RANK; r++) {
                const float* Vrr = Vr + r * S_LEN;
                const float* Vir = Vi + r * S_LEN;
                float wkr = Vrr[k], wki = Vir[k];
                float wjr = Vrr[j], wji = Vir[j];
                float us = fmaf(jm, wjr, wkr);
                float ud = fmaf(-jm, wjr, wkr);
                float vs = fmaf(jm, wji, wki);
                float vd = fmaf(-jm, wji, wki);
                qAr[r] += zar * us - zai * vd;
                qAi[r] += zar * vs + zai * ud;
                qBr[r] += zbr * us - zbi * vd;
                qBi[r] += zbr * vs + zbi * ud;
            }
        }
        if (t == 0) {
            float ar = sre[2048], ai = sim[2048];
            float zar = gA[2048] * (ar + ar);
            float zbr = gB[2048] * (ai + ai);
#pragma unroll
            for (int r = 0; r < RANK; r++) {
                float wkr = Vr[r * S_LEN + 2048], wki = Vi[r * S_LEN + 2048];
                qAr[r] += zar * wkr;  qAi[r] += zar * wki;
                qBr[r] += zbr * wkr;  qBi[r] += zbr * wki;
            }
        }
#pragma unroll
        for (int r = 0; r < RANK; r++) {
#pragma unroll
            for (int off = 16; off > 0; off >>= 1) {
                qAr[r] += __shfl_xor(qAr[r], off, 64);
                qAi[r] += __shfl_xor(qAi[r], off, 64);
                qBr[r] += __shfl_xor(qBr[r], off, 64);
                qBi[r] += __shfl_xor(qBi[r], off, 64);
            }
        }
        if ((lane & 31) == 0) {
            int g = wid * 2 + (lane >> 5);
#pragma unroll
            for (int r = 0; r < RANK; r++) {
                red[g * 32 + r]      = qAr[r];
                red[g * 32 + 8 + r]  = qAi[r];
                red[g * 32 + 16 + r] = qBr[r];
                red[g * 32 + 24 + r] = qBi[r];
            }
        }
        __syncthreads();
        if (t < 32) {
            float v = 0.0f;
#pragma unroll
            for (int g = 0; g < 16; g++) v += red[g * 32 + t];
            pqs[32 + t] = v;
        }
        __syncthreads();
        if (t < 8) {
            float paR = pqs[t],      paI = pqs[8 + t];
            float pbR = pqs[16 + t], pbI = pqs[24 + t];
            float qaR = pqs[32 + t], qaI = pqs[40 + t];
            float qbR = pqs[48 + t], qbI = pqs[56 + t];
            gam4[t] = make_float4(
                0.5f * (paR * qaR + paI * qaI),    // 0.5*gamAr (H's Hermitian 0.5 folded)
                0.5f * (paI * qaR - paR * qaI),    // 0.5*gamAi
                0.5f * (pbR * qbR + pbI * qbI),    // 0.5*gamBr
                0.5f * (pbI * qbR - pbR * qbI));   // 0.5*gamBi
        }
        __syncthreads();
    }

    // ===== phase H: z += upd, Hermitian part, pack w2 = H_a + i H_b.
    // gam4 prescaled by 0.5 -> H combine is pure adds. Register-lean body +
    // NO outer unroll (one ~45-reg body live at a time).
    {
        auto do_pair = [&](int k){
            int j = (S_LEN - k) & (S_LEN - 1);
            float ar = sre[k], ai = sim[k];
            float br = sre[j], bi = sim[j];
            float ga = gA[k], gb = gB[k];       // prescaled 0.5*g (own-slot)
            float zar = ga*(ar + br), zai = ga*(ai - bi);
            float zbr = gb*(ai + bi), zbi = gb*(br - ar);

            float uakr=0.f, uaki=0.f, ubkr=0.f, ubki=0.f;
            {
                const float4* WRk = (const float4*)(Wr + (size_t)k * RANK);
                const float4* WIk = (const float4*)(Wi + (size_t)k * RANK);
#pragma unroll
                for (int h2 = 0; h2 < 2; ++h2){
                    float4 w4 = WRk[h2], y4 = WIk[h2];
                    float4 g0 = gam4[4*h2+0];
                    uakr += g0.x*w4.x - g0.y*y4.x;  uaki += g0.x*y4.x + g0.y*w4.x;
                    ubkr += g0.z*w4.x - g0.w*y4.x;  ubki += g0.z*y4.x + g0.w*w4.x;
                    float4 g1 = gam4[4*h2+1];
                    uakr += g1.x*w4.y - g1.y*y4.y;  uaki += g1.x*y4.y + g1.y*w4.y;
                    ubkr += g1.z*w4.y - g1.w*y4.y;  ubki += g1.z*y4.y + g1.w*w4.y;
                    float4 g2 = gam4[4*h2+2];
                    uakr += g2.x*w4.z - g2.y*y4.z;  uaki += g2.x*y4.z + g2.y*w4.z;
                    ubkr += g2.z*w4.z - g2.w*y4.z;  ubki += g2.z*y4.z + g2.w*w4.z;
                    float4 g3 = gam4[4*h2+3];
                    uakr += g3.x*w4.w - g3.y*y4.w;  uaki += g3.x*y4.w + g3.y*w4.w;
                    ubkr += g3.z*w4.w - g3.w*y4.w;  ubki += g3.z*y4.w + g3.w*w4.w;
                }
            }
            float uajr=0.f, uaji=0.f, ubjr=0.f, ubji=0.f;
            {
                const float4* WRj = (const float4*)(Wr + (size_t)j * RANK);
                const float4* WIj = (const float4*)(Wi + (size_t)j * RANK);
#pragma unroll
                for (int h2 = 0; h2 < 2; ++h2){
                    float4 w4 = WRj[h2], y4 = WIj[h2];
                    float4 g0 = gam4[4*h2+0];
                    uajr += g0.x*w4.x - g0.y*y4.x;  uaji += g0.x*y4.x + g0.y*w4.x;
                    ubjr += g0.z*w4.x - g0.w*y4.x;  ubji += g0.z*y4.x + g0.w*w4.x;
                    float4 g1 = gam4[4*h2+1];
                    uajr += g1.x*w4.y - g1.y*y4.y;  uaji += g1.x*y4.y + g1.y*w4.y;
                    ubjr += g1.z*w4.y - g1.w*y4.y;  ubji += g1.z*y4.y + g1.w*w4.y;
                    float4 g2 = gam4[4*h2+2];
                    uajr += g2.x*w4.z - g2.y*y4.z;  uaji += g2.x*y4.z + g2.y*w4.z;
                    ubjr += g2.z*w4.z - g2.w*y4.z;  ubji += g2.z*y4.z + g2.w*w4.z;
                    float4 g3 = gam4[4*h2+3];
                    uajr += g3.x*w4.w - g3.y*y4.w;  uaji += g3.x*y4.w + g3.y*w4.w;
                    ubjr += g3.z*w4.w - g3.w*y4.w;  ubji += g3.z*y4.w + g3.w*w4.w;
                }
            }
            float HaR = zar + (uakr + uajr);
            float HaI = zai + (uaki - uaji);
            float HbR = zbr + (ubkr + ubjr);
            float HbI = zbi + (ubki - ubji);
            sre[k] = HaR - HbI;  sim[k] = HaI + HbR;
            sre[j] = HaR + HbI;  sim[j] = HbR - HaI;
        };
#pragma unroll 1
        for (int i = 0; i < 4; i++) do_pair(t + 512 * i);   // k = 0..2047
        if (t == 0) do_pair(2048);                          // self-pair
    }
    __syncthreads();   // all w2 written before inverse FFT reads

    // ================= inverse FFT: out_a = Re, out_b = Im =================
    {
#pragma unroll
        for (int c=0;c<8;c++){ ur[c] = sre[t + 512*c]; ui[c] = sim[t + 512*c]; }
        dft8<1>(ur, ui);
        __syncthreads();   // w2 consumed before A overwrites
#pragma unroll
        for (int e=0;e<8;e++){ sre[baseA + 64*e] = ur[e]; sim[baseA + 64*e] = ui[e]; }
    }
    __syncthreads();
    {
#pragma unroll
        for (int m=0;m<8;m++){ ur[m] = sre[t + 512*m]; ui[m] = sim[t + 512*m]; }
        twiddle8<1>(ur, ui, (float)(t >> 6) * (1.0f/64.0f));
        dft8<1>(ur, ui);
        __syncthreads();
#pragma unroll
        for (int e=0;e<8;e++){ sre[baseB + 64*e] = ur[e]; sim[baseB + 64*e] = ui[e]; }
    }
    __syncthreads();
    {
#pragma unroll
        for (int m=0;m<8;m++){ ur[m] = sre[t + 520*m]; ui[m] = sim[t + 520*m]; }
        twiddle8<1>(ur, ui, (float)(t >> 3) * (1.0f/512.0f));
        dft8<1>(ur, ui);
        __syncthreads();
#pragma unroll
        for (int e=0;e<8;e++){ sre[baseC + 64*e] = ur[e]; sim[baseC + 64*e] = ui[e]; }
    }
    __syncthreads();
    {
#pragma unroll
        for (int m=0;m<8;m++){ ur[m] = sre[t + 520*m]; ui[m] = sim[t + 520*m]; }
        twiddle8<1>(ur, ui, (float)t * (1.0f/4096.0f));
        dft8<1>(ur, ui);
        float* orow_a = out + (size_t)(2 * pairidx) * S_LEN;
        float* orow_b = orow_a + S_LEN;
        const float scale = 1.0f / (float)S_LEN;
#pragma unroll
        for (int e=0;e<8;e++){
            orow_a[t + 512*e] = ur[e] * scale;   // Re -> row a
            orow_b[t + 512*e] = ui[e] * scale;   // Im -> row b
        }
    }
}

extern "C" void kernel_launch(void* const* d_in, const int* in_sizes, int n_in,
                              void* d_out, int out_size, void* d_ws, size_t ws_size,
                              hipStream_t stream) {
    const float* x    = (const float*)d_in[0];
    const float* Ur   = (const float*)d_in[1];
    const float* Ui   = (const float*)d_in[2];
    const float* Vr   = (const float*)d_in[3];
    const float* Vi   = (const float*)d_in[4];
    const float* Wr   = (const float*)d_in[5];
    const float* Wi   = (const float*)d_in[6];
    const float* P1w  = (const float*)d_in[7];
    const float* P1b  = (const float*)d_in[8];
    const float* P2w  = (const float*)d_in[9];
    const float* P2b  = (const float*)d_in[10];
    const float* alph = (const float*)d_in[11];

    recip_mixer<<<dim3(1024), dim3(NT), 0, stream>>>(
        x, Ur, Ui, Vr, Vi, Wr, Wi, P1w, P1b, P2w, P2b, alph, (float*)d_out);
}

// Round 13
// 184.964 us; speedup vs baseline: 1.0494x; 1.0494x over previous
//
#include <hip/hip_runtime.h>

#define S_LEN 4096
#define NT 512
#define PER 8
#define RANK 8
#define BP 4160      // padded FFT buffer float count (max transpose addr 4151)
#define NHALF 2049   // half-spectrum gain table (k = 0..2048)
#define TWO_PI 6.2831853071795864769f

__device__ __forceinline__ void cmul(float& xr, float& xi, float cr, float ci){
    float tr = xr*cr - xi*ci;
    xi = xr*ci + xi*cr;
    xr = tr;
}

// 4-point DFT, in place. SIGN=-1 forward, SIGN=+1 inverse.
template<int SIGN>
__device__ __forceinline__ void dft4(float& ar,float& ai,float& br,float& bi,
                                     float& cr,float& ci,float& dr,float& di){
    float Ar=ar+cr, Ai=ai+ci;
    float Br=ar-cr, Bi=ai-ci;
    float Cr=br+dr, Ci=bi+di;
    float Dr, Di;
    if (SIGN < 0){ Dr = bi-di; Di = dr-br; }
    else         { Dr = di-bi; Di = br-dr; }
    ar=Ar+Cr; ai=Ai+Ci;
    br=Br+Dr; bi=Bi+Di;
    cr=Ar-Cr; ci=Ai-Ci;
    dr=Br-Dr; di=Bi-Di;
}

// 8-point DFT in registers, natural-order in and out.
// W8^{1,3} twiddles h-factored: 2 add + 2 mul each (vs 4m+2a cmul); verified
// both signs; kept from r12 (pure op deletion, no pipeline change).
template<int SIGN>
__device__ __forceinline__ void dft8(float ur[8], float ui[8]){
    const float h = 0.70710678118654752f;
    float er0=ur[0], ei0=ui[0], er1=ur[2], ei1=ui[2];
    float er2=ur[4], ei2=ui[4], er3=ur[6], ei3=ui[6];
    float fr0=ur[1], fi0=ui[1], fr1=ur[3], fi1=ui[3];
    float fr2=ur[5], fi2=ui[5], fr3=ur[7], fi3=ui[7];
    dft4<SIGN>(er0,ei0, er1,ei1, er2,ei2, er3,ei3);
    dft4<SIGN>(fr0,fi0, fr1,fi1, fr2,fi2, fr3,fi3);
    {   float a = fr1, b = fi1;
        if (SIGN < 0){ fr1 = h*(a + b); fi1 = h*(b - a); }
        else         { fr1 = h*(a - b); fi1 = h*(a + b); }
    }
    {   float tr = fr2, ti = fi2;
        if (SIGN < 0){ fr2 =  ti; fi2 = -tr; }
        else         { fr2 = -ti; fi2 =  tr; }
    }
    {   float a = fr3, b = fi3;
        if (SIGN < 0){ fr3 = h*(b - a); fi3 = -h*(a + b); }
        else         { fr3 = -h*(a + b); fi3 = h*(a - b); }
    }
    ur[0]=er0+fr0; ui[0]=ei0+fi0;
    ur[1]=er1+fr1; ui[1]=ei1+fi1;
    ur[2]=er2+fr2; ui[2]=ei2+fi2;
    ur[3]=er3+fr3; ui[3]=ei3+fi3;
    ur[4]=er0-fr0; ui[4]=ei0-fi0;
    ur[5]=er1-fr1; ui[5]=ei1-fi1;
    ur[6]=er2-fr2; ui[6]=ei2-fi2;
    ur[7]=er3-fr3; ui[7]=ei3-fi3;
}

// balanced-tree twiddle powers (dep depth 3) + apply. __sincosf RESTORED
// (r12's raw v_sin/v_cos builtins correlated with a +60us stall — shelved).
template<int SIGN>
__device__ __forceinline__ void twiddle8(float ur[8], float ui[8], float theta){
    float s, c;
    __sincosf(theta, &s, &c);
    const float w1i = (SIGN < 0) ? -s : s;
    const float w1r = c;
    float w2r = w1r*w1r - w1i*w1i, w2i = 2.0f*w1r*w1i;
    float w3r = w2r*w1r - w2i*w1i, w3i = w2r*w1i + w2i*w1r;
    float w4r = w2r*w2r - w2i*w2i, w4i = 2.0f*w2r*w2i;
    float w5r = w4r*w1r - w4i*w1i, w5i = w4r*w1i + w4i*w1r;
    float w6r = w3r*w3r - w3i*w3i, w6i = 2.0f*w3r*w3i;
    float w7r = w4r*w3r - w4i*w3i, w7i = w4r*w3i + w4i*w3r;
    cmul(ur[1], ui[1], w1r, w1i);
    cmul(ur[2], ui[2], w2r, w2i);
    cmul(ur[3], ui[3], w3r, w3i);
    cmul(ur[4], ui[4], w4r, w4i);
    cmul(ur[5], ui[5], w5r, w5i);
    cmul(ur[6], ui[6], w6r, w6i);
    cmul(ur[7], ui[7], w7r, w7i);
}

// gain for spectral index k (0..2048) for BOTH rows at once (shared bg + gathers).
__device__ __forceinline__ void gain_pair(int k, const float* hhA, const float* hhB,
    float alpha, const float* __restrict__ P2w, const float* __restrict__ P2b,
    float& ga, float& gb){
    float nf = (float)k * (1.0f/2048.0f);
    float tt = nf * 5.0f;
    float lb = __expf(-0.5f * tt * tt);
    float hd = 0.5f / (1.0f + __expf(-(nf - 0.6f) * 10.0f));
    float bg = fmaxf(1.0f + lb - hd, 0.0f);
    float scaled = nf * 4095.0f;
    float fl = floorf(scaled);
    int lo = (int)fl;
    int hi = (int)ceilf(scaled);
    float fr = scaled - fl;
    const float4* p2lo = (const float4*)(P2w + (size_t)lo * RANK);
    const float4* p2hi = (const float4*)(P2w + (size_t)hi * RANK);
    float4 a0 = p2lo[0], a1 = p2lo[1];
    float4 b0 = p2hi[0], b1 = p2hi[1];
    float blo = P2b[lo], bhi = P2b[hi];
    float dAlo = blo + hhA[0]*a0.x + hhA[1]*a0.y + hhA[2]*a0.z + hhA[3]*a0.w
                     + hhA[4]*a1.x + hhA[5]*a1.y + hhA[6]*a1.z + hhA[7]*a1.w;
    float dAhi = bhi + hhA[0]*b0.x + hhA[1]*b0.y + hhA[2]*b0.z + hhA[3]*b0.w
                     + hhA[4]*b1.x + hhA[5]*b1.y + hhA[6]*b1.z + hhA[7]*b1.w;
    float dBlo = blo + hhB[0]*a0.x + hhB[1]*a0.y + hhB[2]*a0.z + hhB[3]*a0.w
                     + hhB[4]*a1.x + hhB[5]*a1.y + hhB[6]*a1.z + hhB[7]*a1.w;
    float dBhi = bhi + hhB[0]*b0.x + hhB[1]*b0.y + hhB[2]*b0.z + hhB[3]*b0.w
                     + hhB[4]*b1.x + hhB[5]*b1.y + hhB[6]*b1.z + hhB[7]*b1.w;
    float dA = dAlo + (dAhi - dAlo) * fr;
    float dB = dBlo + (dBhi - dBlo) * fr;
    ga = fmaxf(bg + alpha * dA, 0.0f);
    gb = fmaxf(bg + alpha * dB, 0.0f);
}

// ============================================================================
// r13 = r11 (best: 108us dispatch / 184.9us harness) + ONLY the two
// pure-arithmetic folds from r12 (op deletions on existing dataflow):
//   - gA/gB and gam4 prescaled by 0.5 at their single write sites; H-combine
//     pure adds; self-pairs exact (za = 0.5g*2ar = g*ar).
//   - dft8 h-factored W8^{1,3}.
// REVERTED from r12 (correlated with +60us stall, unattributed):
//   - raw v_sin/v_cos builtins -> __sincosf restored.
//   - 5-step reduction/16-partial combine -> 6-step shfl + 8 partials, red[256].
// Unroll discipline (r10): "#pragma unroll 1" on ALL big outer loops.
// VGPR wall (r2-r7): 64 -> 4 waves/SIMD; <64 cap spills. 2 blocks/CU.
// ============================================================================

__global__ __launch_bounds__(NT, 4) void recip_mixer(
    const float* __restrict__ x,
    const float* __restrict__ Ur, const float* __restrict__ Ui,
    const float* __restrict__ Vr, const float* __restrict__ Vi,
    const float* __restrict__ Wr, const float* __restrict__ Wi,
    const float* __restrict__ P1w, const float* __restrict__ P1b,
    const float* __restrict__ P2w, const float* __restrict__ P2b,
    const float* __restrict__ alphap,
    float* __restrict__ out)
{
    __shared__ float sre[BP], sim[BP];
    __shared__ float gA[NHALF], gB[NHALF];   // PRESCALED by 0.5
    __shared__ float red[256];
    __shared__ float hidA[RANK], hidB[RANK];
    __shared__ float4 gam4[RANK];   // {gamAr, gamAi, gamBr, gamBi}, PRESCALED by 0.5
    __shared__ float pqs[64];

    const int t    = threadIdx.x;
    const int pairidx = blockIdx.x;
    const int lane = t & 63;
    const int wid  = t >> 6;

    float ur[8], ui[8];

    const int baseA = (t & 63) + 512 * (t >> 6);
    const int baseB = (t & 7) + 8*(t >> 6) + 520*((t >> 3) & 7);
    const int baseC = (t >> 3) + 520*(t & 7);

    const float* xa = x + (size_t)(2 * pairidx) * S_LEN;
    const float* xb = xa + S_LEN;

    // ================= forward FFT of w = x_a + i x_b =================
    {
#pragma unroll
        for (int c=0;c<8;c++){ ur[c] = xa[t + 512*c]; ui[c] = xb[t + 512*c]; }
        dft8<-1>(ur, ui);
#pragma unroll
        for (int e=0;e<8;e++){ sre[baseA + 64*e] = ur[e]; sim[baseA + 64*e] = ui[e]; }
    }
    __syncthreads();
    {
#pragma unroll
        for (int m=0;m<8;m++){ ur[m] = sre[t + 512*m]; ui[m] = sim[t + 512*m]; }
        twiddle8<-1>(ur, ui, TWO_PI * (float)(t >> 6) * (1.0f/64.0f));
        dft8<-1>(ur, ui);
        __syncthreads();
#pragma unroll
        for (int e=0;e<8;e++){ sre[baseB + 64*e] = ur[e]; sim[baseB + 64*e] = ui[e]; }
    }
    __syncthreads();
    {
#pragma unroll
        for (int m=0;m<8;m++){ ur[m] = sre[t + 520*m]; ui[m] = sim[t + 520*m]; }
        twiddle8<-1>(ur, ui, TWO_PI * (float)(t >> 3) * (1.0f/512.0f));
        dft8<-1>(ur, ui);
        __syncthreads();
#pragma unroll
        for (int e=0;e<8;e++){ sre[baseC + 64*e] = ur[e]; sim[baseC + 64*e] = ui[e]; }
    }
    __syncthreads();
    {
#pragma unroll
        for (int m=0;m<8;m++){ ur[m] = sre[t + 520*m]; ui[m] = sim[t + 520*m]; }
        twiddle8<-1>(ur, ui, TWO_PI * (float)t * (1.0f/4096.0f));
        dft8<-1>(ur, ui);
        __syncthreads();
#pragma unroll
        for (int e=0;e<8;e++){ sre[t + 512*e] = ur[e]; sim[t + 512*e] = ui[e]; }
    }
    __syncthreads();   // middle phases read other threads' (k, N-k) slots

    // ===== phase 1: hidden for BOTH rows — pair-based (4 pairs/thread)
    {
        float ha[RANK], hb[RANK];
#pragma unroll
        for (int r = 0; r < RANK; r++){ ha[r] = 0.0f; hb[r] = 0.0f; }
#pragma unroll 1
        for (int i = 0; i < 4; i++) {
            int k = t + 512 * i;
            int j = (S_LEN - k) & (S_LEN - 1);
            float jm = (k == 0) ? 0.0f : 1.0f;   // kill j-side weights for self-pair
            float ar = sre[k], ai = sim[k];
            float br = sre[j], bi = sim[j];
            float zar = 0.5f*(ar + br), zai = 0.5f*(ai - bi);
            float zbr = 0.5f*(ai + bi), zbi = 0.5f*(br - ar);
#pragma unroll
            for (int r = 0; r < RANK; r++) {
                const float* P1r = P1w + r * (2 * S_LEN);
                float p0k = P1r[k],        p1k = P1r[S_LEN + k];
                float p0j = P1r[j],        p1j = P1r[S_LEN + j];
                float us = fmaf(jm, p0j, p0k);    // p0k + p0j
                float ud = fmaf(-jm, p1j, p1k);   // p1k - p1j
                ha[r] += zar * us + zai * ud;
                hb[r] += zbr * us + zbi * ud;
            }
        }
        if (t == 0) {
            // self-pair k = 2048: za = Re W (zai=0), zb = Im W (zbi=0)
            float ar = sre[2048], ai = sim[2048];
#pragma unroll
            for (int r = 0; r < RANK; r++) {
                float p0 = P1w[r * (2 * S_LEN) + 2048];
                ha[r] += ar * p0;
                hb[r] += ai * p0;
            }
        }
#pragma unroll
        for (int r = 0; r < RANK; r++) {
#pragma unroll
            for (int off = 32; off > 0; off >>= 1){
                ha[r] += __shfl_xor(ha[r], off, 64);
                hb[r] += __shfl_xor(hb[r], off, 64);
            }
        }
        if (lane == 0) {
#pragma unroll
            for (int r = 0; r < RANK; r++){
                red[wid * 16 + r]     = ha[r];
                red[wid * 16 + 8 + r] = hb[r];
            }
        }
        __syncthreads();
        if (t < 16) {
            float v = 0.0f;
#pragma unroll
            for (int w = 0; w < 8; w++) v += red[w * 16 + t];
            float res = fmaxf(v + P1b[t & 7], 0.0f);
            if (t < 8) hidA[t] = res; else hidB[t - 8] = res;
        }
        __syncthreads();
    }

    // ===== phase 2a: half-spectrum gain tables gA/gB[0..2048], PRESCALED 0.5
    // (each thread writes only its own k set {t+512i} (+2048 by t0); all later
    //  reads are by the SAME thread -> no barrier needed after this phase)
    {
        float hhA[RANK], hhB[RANK];
#pragma unroll
        for (int r = 0; r < RANK; r++){ hhA[r] = hidA[r]; hhB[r] = hidB[r]; }
        const float alpha = alphap[0];
#pragma unroll 1
        for (int i = 0; i < 4; i++) {
            int k = t + 512 * i;           // 0..2047
            float ga, gb;
            gain_pair(k, hhA, hhB, alpha, P2w, P2b, ga, gb);
            gA[k] = 0.5f * ga; gB[k] = 0.5f * gb;
        }
        if (t == 0) {
            float ga, gb;
            gain_pair(2048, hhA, hhB, alpha, P2w, P2b, ga, gb);
            gA[2048] = 0.5f * ga; gB[2048] = 0.5f * gb;
        }
    }
    // no __syncthreads: own-slot gain reads only from here on

    // ===== phase 2b p-pass: pair-based (4 pairs/thread), rows A+B
    {
        float pAr[RANK], pAi[RANK], pBr[RANK], pBi[RANK];
#pragma unroll
        for (int r = 0; r < RANK; r++){ pAr[r]=0.f; pAi[r]=0.f; pBr[r]=0.f; pBi[r]=0.f; }
#pragma unroll 1
        for (int i = 0; i < 4; i++) {
            int k = t + 512 * i;
            int j = (S_LEN - k) & (S_LEN - 1);
            float jm = (k == 0) ? 0.0f : 1.0f;
            float ar = sre[k], ai = sim[k];
            float br = sre[j], bi = sim[j];
            float ga = gA[k], gb = gB[k];       // prescaled 0.5*g
            float zar = ga*(ar + br), zai = ga*(ai - bi);
            float zbr = gb*(ai + bi), zbi = gb*(br - ar);
#pragma unroll
            for (int r = 0; r < RANK; r++) {
                const float* Urr = Ur + r * S_LEN;
                const float* Uir = Ui + r * S_LEN;
                float ukr = Urr[k], uki = Uir[k];
                float ujr = Urr[j], uji = Uir[j];
                float us = fmaf(jm, ujr, ukr);    // ukr + ujr
                float ud = fmaf(-jm, ujr, ukr);   // ukr - ujr
                float vs = fmaf(jm, uji, uki);    // uki + uji
                float vd = fmaf(-jm, uji, uki);   // uki - uji
                pAr[r] += zar * us - zai * vd;
                pAi[r] += zar * vs + zai * ud;
                pBr[r] += zbr * us - zbi * vd;
                pBi[r] += zbr * vs + zbi * ud;
            }
        }
        if (t == 0) {
            float ar = sre[2048], ai = sim[2048];
            float zar = gA[2048] * (ar + ar);   // = g*ar (gain prescaled)
            float zbr = gB[2048] * (ai + ai);   // = g*ai
#pragma unroll
            for (int r = 0; r < RANK; r++) {
                float ukr = Ur[r * S_LEN + 2048], uki = Ui[r * S_LEN + 2048];
                pAr[r] += zar * ukr;  pAi[r] += zar * uki;
                pBr[r] += zbr * ukr;  pBi[r] += zbr * uki;
            }
        }
#pragma unroll
        for (int r = 0; r < RANK; r++) {
#pragma unroll
            for (int off = 32; off > 0; off >>= 1) {
                pAr[r] += __shfl_xor(pAr[r], off, 64);
                pAi[r] += __shfl_xor(pAi[r], off, 64);
                pBr[r] += __shfl_xor(pBr[r], off, 64);
                pBi[r] += __shfl_xor(pBi[r], off, 64);
            }
        }
        if (lane == 0) {
#pragma unroll
            for (int r = 0; r < RANK; r++) {
                red[wid * 32 + r]      = pAr[r];
                red[wid * 32 + 8 + r]  = pAi[r];
                red[wid * 32 + 16 + r] = pBr[r];
                red[wid * 32 + 24 + r] = pBi[r];
            }
        }
        __syncthreads();
        if (t < 32) {
            float v = 0.0f;
#pragma unroll
            for (int w = 0; w < 8; w++) v += red[w * 32 + t];
            pqs[t] = v;
        }
        __syncthreads();
    }

    // ===== phase 2b q-pass: pair-based, rows A+B, then gamma
    {
        float qAr[RANK], qAi[RANK], qBr[RANK], qBi[RANK];
#pragma unroll
        for (int r = 0; r < RANK; r++){ qAr[r]=0.f; qAi[r]=0.f; qBr[r]=0.f; qBi[r]=0.f; }
#pragma unroll 1
        for (int i = 0; i < 4; i++) {
            int k = t + 512 * i;
            int j = (S_LEN - k) & (S_LEN - 1);
            float jm = (k == 0) ? 0.0f : 1.0f;
            float ar = sre[k], ai = sim[k];
            float br = sre[j], bi = sim[j];
            float ga = gA[k], gb = gB[k];       // prescaled 0.5*g
            float zar = ga*(ar + br), zai = ga*(ai - bi);
            float zbr = gb*(ai + bi), zbi = gb*(br - ar);
#pragma unroll
            for (int r = 0; r < RANK; r++) {
                const float* Vrr = Vr + r * S_LEN;
                const float* Vir = Vi + r * S_LEN;
                float wkr = Vrr[k], wki = Vir[k];
                float wjr = Vrr[j], wji = Vir[j];
                float us = fmaf(jm, wjr, wkr);
                float ud = fmaf(-jm, wjr, wkr);
                float vs = fmaf(jm, wji, wki);
                float vd = fmaf(-jm, wji, wki);
                qAr[r] += zar * us - zai * vd;
                qAi[r] += zar * vs + zai * ud;
                qBr[r] += zbr * us - zbi * vd;
                qBi[r] += zbr * vs + zbi * ud;
            }
        }
        if (t == 0) {
            float ar = sre[2048], ai = sim[2048];
            float zar = gA[2048] * (ar + ar);
            float zbr = gB[2048] * (ai + ai);
#pragma unroll
            for (int r = 0; r < RANK; r++) {
                float wkr = Vr[r * S_LEN + 2048], wki = Vi[r * S_LEN + 2048];
                qAr[r] += zar * wkr;  qAi[r] += zar * wki;
                qBr[r] += zbr * wkr;  qBi[r] += zbr * wki;
            }
        }
#pragma unroll
        for (int r = 0; r < RANK; r++) {
#pragma unroll
            for (int off = 32; off > 0; off >>= 1) {
                qAr[r] += __shfl_xor(qAr[r], off, 64);
                qAi[r] += __shfl_xor(qAi[r], off, 64);
                qBr[r] += __shfl_xor(qBr[r], off, 64);
                qBi[r] += __shfl_xor(qBi[r], off, 64);
            }
        }
        if (lane == 0) {
#pragma unroll
            for (int r = 0; r < RANK; r++) {
                red[wid * 32 + r]      = qAr[r];
                red[wid * 32 + 8 + r]  = qAi[r];
                red[wid * 32 + 16 + r] = qBr[r];
                red[wid * 32 + 24 + r] = qBi[r];
            }
        }
        __syncthreads();
        if (t < 32) {
            float v = 0.0f;
#pragma unroll
            for (int w = 0; w < 8; w++) v += red[w * 32 + t];
            pqs[32 + t] = v;
        }
        __syncthreads();
        if (t < 8) {
            float paR = pqs[t],      paI = pqs[8 + t];
            float pbR = pqs[16 + t], pbI = pqs[24 + t];
            float qaR = pqs[32 + t], qaI = pqs[40 + t];
            float qbR = pqs[48 + t], qbI = pqs[56 + t];
            gam4[t] = make_float4(
                0.5f * (paR * qaR + paI * qaI),    // 0.5*gamAr (H's Hermitian 0.5 folded)
                0.5f * (paI * qaR - paR * qaI),    // 0.5*gamAi
                0.5f * (pbR * qbR + pbI * qbI),    // 0.5*gamBr
                0.5f * (pbI * qbR - pbR * qbI));   // 0.5*gamBi
        }
        __syncthreads();
    }

    // ===== phase H: z += upd, Hermitian part, pack w2 = H_a + i H_b.
    // gam4/gains prescaled -> H combine pure adds. Register-lean body +
    // NO outer unroll (one ~45-reg body live at a time).
    {
        auto do_pair = [&](int k){
            int j = (S_LEN - k) & (S_LEN - 1);
            float ar = sre[k], ai = sim[k];
            float br = sre[j], bi = sim[j];
            float ga = gA[k], gb = gB[k];       // prescaled 0.5*g (own-slot)
            float zar = ga*(ar + br), zai = ga*(ai - bi);
            float zbr = gb*(ai + bi), zbi = gb*(br - ar);

            float uakr=0.f, uaki=0.f, ubkr=0.f, ubki=0.f;
            {
                const float4* WRk = (const float4*)(Wr + (size_t)k * RANK);
                const float4* WIk = (const float4*)(Wi + (size_t)k * RANK);
#pragma unroll
                for (int h2 = 0; h2 < 2; ++h2){
                    float4 w4 = WRk[h2], y4 = WIk[h2];
                    float4 g0 = gam4[4*h2+0];
                    uakr += g0.x*w4.x - g0.y*y4.x;  uaki += g0.x*y4.x + g0.y*w4.x;
                    ubkr += g0.z*w4.x - g0.w*y4.x;  ubki += g0.z*y4.x + g0.w*w4.x;
                    float4 g1 = gam4[4*h2+1];
                    uakr += g1.x*w4.y - g1.y*y4.y;  uaki += g1.x*y4.y + g1.y*w4.y;
                    ubkr += g1.z*w4.y - g1.w*y4.y;  ubki += g1.z*y4.y + g1.w*w4.y;
                    float4 g2 = gam4[4*h2+2];
                    uakr += g2.x*w4.z - g2.y*y4.z;  uaki += g2.x*y4.z + g2.y*w4.z;
                    ubkr += g2.z*w4.z - g2.w*y4.z;  ubki += g2.z*y4.z + g2.w*w4.z;
                    float4 g3 = gam4[4*h2+3];
                    uakr += g3.x*w4.w - g3.y*y4.w;  uaki += g3.x*y4.w + g3.y*w4.w;
                    ubkr += g3.z*w4.w - g3.w*y4.w;  ubki += g3.z*y4.w + g3.w*w4.w;
                }
            }
            float uajr=0.f, uaji=0.f, ubjr=0.f, ubji=0.f;
            {
                const float4* WRj = (const float4*)(Wr + (size_t)j * RANK);
                const float4* WIj = (const float4*)(Wi + (size_t)j * RANK);
#pragma unroll
                for (int h2 = 0; h2 < 2; ++h2){
                    float4 w4 = WRj[h2], y4 = WIj[h2];
                    float4 g0 = gam4[4*h2+0];
                    uajr += g0.x*w4.x - g0.y*y4.x;  uaji += g0.x*y4.x + g0.y*w4.x;
                    ubjr += g0.z*w4.x - g0.w*y4.x;  ubji += g0.z*y4.x + g0.w*w4.x;
                    float4 g1 = gam4[4*h2+1];
                    uajr += g1.x*w4.y - g1.y*y4.y;  uaji += g1.x*y4.y + g1.y*w4.y;
                    ubjr += g1.z*w4.y - g1.w*y4.y;  ubji += g1.z*y4.y + g1.w*w4.y;
                    float4 g2 = gam4[4*h2+2];
                    uajr += g2.x*w4.z - g2.y*y4.z;  uaji += g2.x*y4.z + g2.y*w4.z;
                    ubjr += g2.z*w4.z - g2.w*y4.z;  ubji += g2.z*y4.z + g2.w*w4.z;
                    float4 g3 = gam4[4*h2+3];
                    uajr += g3.x*w4.w - g3.y*y4.w;  uaji += g3.x*y4.w + g3.y*w4.w;
                    ubjr += g3.z*w4.w - g3.w*y4.w;  ubji += g3.z*y4.w + g3.w*w4.w;
                }
            }
            float HaR = zar + (uakr + uajr);
            float HaI = zai + (uaki - uaji);
            float HbR = zbr + (ubkr + ubjr);
            float HbI = zbi + (ubki - ubji);
            sre[k] = HaR - HbI;  sim[k] = HaI + HbR;
            sre[j] = HaR + HbI;  sim[j] = HbR - HaI;
        };
#pragma unroll 1
        for (int i = 0; i < 4; i++) do_pair(t + 512 * i);   // k = 0..2047
        if (t == 0) do_pair(2048);                          // self-pair
    }
    __syncthreads();   // all w2 written before inverse FFT reads

    // ================= inverse FFT: out_a = Re, out_b = Im =================
    {
#pragma unroll
        for (int c=0;c<8;c++){ ur[c] = sre[t + 512*c]; ui[c] = sim[t + 512*c]; }
        dft8<1>(ur, ui);
        __syncthreads();   // w2 consumed before A overwrites
#pragma unroll
        for (int e=0;e<8;e++){ sre[baseA + 64*e] = ur[e]; sim[baseA + 64*e] = ui[e]; }
    }
    __syncthreads();
    {
#pragma unroll
        for (int m=0;m<8;m++){ ur[m] = sre[t + 512*m]; ui[m] = sim[t + 512*m]; }
        twiddle8<1>(ur, ui, TWO_PI * (float)(t >> 6) * (1.0f/64.0f));
        dft8<1>(ur, ui);
        __syncthreads();
#pragma unroll
        for (int e=0;e<8;e++){ sre[baseB + 64*e] = ur[e]; sim[baseB + 64*e] = ui[e]; }
    }
    __syncthreads();
    {
#pragma unroll
        for (int m=0;m<8;m++){ ur[m] = sre[t + 520*m]; ui[m] = sim[t + 520*m]; }
        twiddle8<1>(ur, ui, TWO_PI * (float)(t >> 3) * (1.0f/512.0f));
        dft8<1>(ur, ui);
        __syncthreads();
#pragma unroll
        for (int e=0;e<8;e++){ sre[baseC + 64*e] = ur[e]; sim[baseC + 64*e] = ui[e]; }
    }
    __syncthreads();
    {
#pragma unroll
        for (int m=0;m<8;m++){ ur[m] = sre[t + 520*m]; ui[m] = sim[t + 520*m]; }
        twiddle8<1>(ur, ui, TWO_PI * (float)t * (1.0f/4096.0f));
        dft8<1>(ur, ui);
        float* orow_a = out + (size_t)(2 * pairidx) * S_LEN;
        float* orow_b = orow_a + S_LEN;
        const float scale = 1.0f / (float)S_LEN;
#pragma unroll
        for (int e=0;e<8;e++){
            orow_a[t + 512*e] = ur[e] * scale;   // Re -> row a
            orow_b[t + 512*e] = ui[e] * scale;   // Im -> row b
        }
    }
}

extern "C" void kernel_launch(void* const* d_in, const int* in_sizes, int n_in,
                              void* d_out, int out_size, void* d_ws, size_t ws_size,
                              hipStream_t stream) {
    const float* x    = (const float*)d_in[0];
    const float* Ur   = (const float*)d_in[1];
    const float* Ui   = (const float*)d_in[2];
    const float* Vr   = (const float*)d_in[3];
    const float* Vi   = (const float*)d_in[4];
    const float* Wr   = (const float*)d_in[5];
    const float* Wi   = (const float*)d_in[6];
    const float* P1w  = (const float*)d_in[7];
    const float* P1b  = (const float*)d_in[8];
    const float* P2w  = (const float*)d_in[9];
    const float* P2b  = (const float*)d_in[10];
    const float* alph = (const float*)d_in[11];

    recip_mixer<<<dim3(1024), dim3(NT), 0, stream>>>(
        x, Ur, Ui, Vr, Vi, Wr, Wi, P1w, P1b, P2w, P2b, alph, (float*)d_out);
}